// Round 2
// baseline (3460.102 us; speedup 1.0000x reference)
//
#include <hip/hip_runtime.h>
#include <hip/hip_bf16.h>

using bf16 = __hip_bfloat16;

// MaskedMSA: B=4, S=2048, E=1024, HIDDEN=1024, HEADS=16
// Reference reshape mixes seq/hidden: with t=16u+r (u<128, r<16):
//   q[b,h,t,e] = qkv[b, 128h+u, 192r +   0 + e]
//   k[b,h,t,e] = qkv[b, 128h+u, 192r +  64 + e]
//   v[b,h,t,e] = qkv[b, 128h+u, 192r + 128 + e]
// Output: sa[b,h,t,e] -> out row s' = 128h+u, col c' = 64r+e.
// Causal mask applies to permuted index t.
//
// I/O dtype (fp32 vs bf16) is detected at runtime from the data itself and
// handled by an up-front conversion layer; the core pipeline is bf16.

__device__ __forceinline__ void unpack2(unsigned int u, float& a, float& b) {
  union U { unsigned int i; float f; } x, y;
  x.i = u << 16; y.i = u & 0xffff0000u;
  a = x.f; b = y.f;
}

__device__ __forceinline__ unsigned short f2bf(float v) {
  bf16 h = __float2bfloat16(v);
  return *(unsigned short*)&h;
}

// ---- dtype detect: flag=1 if fp32 I/O, flag=0 if bf16 I/O.
// For fp32 words, bits[14:7] are uniform mantissa bits (~15% in-band).
// For packed bf16, bits[14:7] are the low element's exponent (in-band ~always).
__global__ void detect_kernel(const unsigned int* __restrict__ x, int* __restrict__ flag) {
  unsigned int w = x[threadIdx.x];
  unsigned int e = (w >> 7) & 0xFF;
  bool inband = (e >= 96 && e <= 133);
  unsigned long long m = __ballot(inband);
  if (threadIdx.x == 0) flag[0] = (__popcll(m) >= 48) ? 0 : 1;
}

// ---- convert n8*8 elements to bf16 (copy if already bf16)
__global__ __launch_bounds__(256) void convert_kernel(
    const void* __restrict__ src, bf16* __restrict__ dst, int n8,
    const int* __restrict__ flag) {
  int i = blockIdx.x * 256 + threadIdx.x;
  if (i >= n8) return;
  uint4 outv;
  if (*flag) {
    const float4* s = (const float4*)src + (size_t)i * 2;
    float4 a = s[0], b = s[1];
    outv.x = f2bf(a.x) | ((unsigned)f2bf(a.y) << 16);
    outv.y = f2bf(a.z) | ((unsigned)f2bf(a.w) << 16);
    outv.z = f2bf(b.x) | ((unsigned)f2bf(b.y) << 16);
    outv.w = f2bf(b.z) | ((unsigned)f2bf(b.w) << 16);
  } else {
    outv = ((const uint4*)src)[i];
  }
  ((uint4*)dst)[i] = outv;
}

// ---------------- GEMM: C[M,N] = A[M,K] @ B[K,N] + bias; bf16 in, fp32 accum.
// store_mode==0: C is bf16. store_mode==1: C dtype follows *flag (fp32 or bf16).
__global__ __launch_bounds__(256) void gemm_bias(
    const bf16* __restrict__ A, const bf16* __restrict__ Bm,
    const bf16* __restrict__ bias, void* __restrict__ C,
    int M, int N, int K, int store_mode, const int* __restrict__ flag)
{
  __shared__ float As[16][68];  // [k][m]
  __shared__ float Bs[16][68];  // [k][n]
  const bool store_f32 = store_mode && (*flag != 0);
  const int tid = threadIdx.x;
  const int n0 = blockIdx.x * 64;
  const int m0 = blockIdx.y * 64;
  const int tx = tid & 15, ty = tid >> 4;
  const int arow = tid >> 2, acol = (tid & 3) << 2;   // A: 64 rows x 16 k
  const int brow = tid >> 4, bcol = (tid & 15) << 2;  // B: 16 k x 64 n
  float acc[4][4] = {};
  for (int k0 = 0; k0 < K; k0 += 16) {
    __syncthreads();
    {
      const unsigned short* p = (const unsigned short*)A + (size_t)(m0 + arow) * K + (k0 + acol);
      uint2 v = *(const uint2*)p;
      float f0, f1, f2, f3; unpack2(v.x, f0, f1); unpack2(v.y, f2, f3);
      As[acol + 0][arow] = f0; As[acol + 1][arow] = f1;
      As[acol + 2][arow] = f2; As[acol + 3][arow] = f3;
    }
    {
      const unsigned short* p = (const unsigned short*)Bm + (size_t)(k0 + brow) * N + (n0 + bcol);
      uint2 v = *(const uint2*)p;
      float f0, f1, f2, f3; unpack2(v.x, f0, f1); unpack2(v.y, f2, f3);
      Bs[brow][bcol + 0] = f0; Bs[brow][bcol + 1] = f1;
      Bs[brow][bcol + 2] = f2; Bs[brow][bcol + 3] = f3;
    }
    __syncthreads();
#pragma unroll
    for (int kk = 0; kk < 16; ++kk) {
      const float4 av = *(const float4*)&As[kk][ty * 4];
      const float4 bv = *(const float4*)&Bs[kk][tx * 4];
      float a[4] = {av.x, av.y, av.z, av.w};
      float b[4] = {bv.x, bv.y, bv.z, bv.w};
#pragma unroll
      for (int i = 0; i < 4; ++i)
#pragma unroll
        for (int j = 0; j < 4; ++j)
          acc[i][j] = fmaf(a[i], b[j], acc[i][j]);
    }
  }
#pragma unroll
  for (int i = 0; i < 4; ++i) {
    const int mm = m0 + ty * 4 + i;
#pragma unroll
    for (int j = 0; j < 4; ++j) {
      const int nn = n0 + tx * 4 + j;
      float o = acc[i][j] + __bfloat162float(bias[nn]);
      if (store_f32) ((float*)C)[(size_t)mm * N + nn] = o;
      else           ((bf16*)C)[(size_t)mm * N + nn] = __float2bfloat16(o);
    }
  }
}

// ---------------- Flash-style causal attention on the permuted layout
// grid: (32 q-tiles, 64 bh). 256 threads: 4 lanes per query row (row=tid>>2, cg=tid&3).
__global__ __launch_bounds__(256) void attn(const bf16* __restrict__ qkv,
                                            bf16* __restrict__ sa)
{
  __shared__ float Qs[64][65];
  __shared__ float Ks[64][65];
  __shared__ float Vs[64][68];
  const int tid = threadIdx.x;
  const int qt = blockIdx.x;
  const int bh = blockIdx.y;
  const int b = bh >> 4, h = bh & 15;
  const size_t base = ((size_t)(b * 2048 + h * 128)) * 3072;
  const float scale = 0.022097086912079608f;  // (2*1024)^-0.5

#pragma unroll
  for (int it = 0; it < 2; ++it) {
    int vid = tid + it * 256;
    int qr = vid >> 3;
    int vcol = (vid & 7) << 3;
    int t = qt * 64 + qr;
    int u = t >> 4, r = t & 15;
    const unsigned short* p = (const unsigned short*)qkv + base + (size_t)u * 3072 + r * 192 + vcol;
    uint4 v = *(const uint4*)p;
    float f[8];
    unpack2(v.x, f[0], f[1]); unpack2(v.y, f[2], f[3]);
    unpack2(v.z, f[4], f[5]); unpack2(v.w, f[6], f[7]);
#pragma unroll
    for (int j = 0; j < 8; ++j) Qs[qr][vcol + j] = f[j] * scale;
  }

  const int row = tid >> 2;
  const int cg = tid & 3;
  const int tq = qt * 64 + row;
  float m = -__builtin_inff(), l = 0.f;
  float o[16];
#pragma unroll
  for (int j = 0; j < 16; ++j) o[j] = 0.f;

  for (int kt = 0; kt <= qt; ++kt) {
    __syncthreads();
#pragma unroll
    for (int it = 0; it < 2; ++it) {
      int vid = tid + it * 256;
      int kr = vid >> 3;
      int vcol = (vid & 7) << 3;
      int t = kt * 64 + kr;
      int u = t >> 4, r = t & 15;
      const unsigned short* pk = (const unsigned short*)qkv + base + (size_t)u * 3072 + r * 192 + 64 + vcol;
      uint4 vk = *(const uint4*)pk;
      uint4 vv = *(const uint4*)(pk + 64);
      float fk[8], fv[8];
      unpack2(vk.x, fk[0], fk[1]); unpack2(vk.y, fk[2], fk[3]);
      unpack2(vk.z, fk[4], fk[5]); unpack2(vk.w, fk[6], fk[7]);
      unpack2(vv.x, fv[0], fv[1]); unpack2(vv.y, fv[2], fv[3]);
      unpack2(vv.z, fv[4], fv[5]); unpack2(vv.w, fv[6], fv[7]);
#pragma unroll
      for (int j = 0; j < 8; ++j) { Ks[kr][vcol + j] = fk[j]; Vs[kr][vcol + j] = fv[j]; }
    }
    __syncthreads();

    float s[16];
#pragma unroll
    for (int j = 0; j < 16; ++j) s[j] = 0.f;
    for (int e = 0; e < 64; ++e) {
      float qv = Qs[row][e];
#pragma unroll
      for (int j = 0; j < 16; ++j) s[j] = fmaf(qv, Ks[cg * 16 + j][e], s[j]);
    }
    if (kt == qt) {
#pragma unroll
      for (int j = 0; j < 16; ++j) {
        int tk = kt * 64 + cg * 16 + j;
        if (tk > tq) s[j] = -__builtin_inff();
      }
    }
    float mt = s[0];
#pragma unroll
    for (int j = 1; j < 16; ++j) mt = fmaxf(mt, s[j]);
    mt = fmaxf(mt, __shfl_xor(mt, 1, 64));
    mt = fmaxf(mt, __shfl_xor(mt, 2, 64));
    float m_new = fmaxf(m, mt);
    float alpha = __expf(m - m_new);
    float sum = 0.f;
#pragma unroll
    for (int j = 0; j < 16; ++j) {
      float p = __expf(s[j] - m_new);
      s[j] = p;
      sum += p;
    }
    sum += __shfl_xor(sum, 1, 64);
    sum += __shfl_xor(sum, 2, 64);
    l = l * alpha + sum;
    m = m_new;
#pragma unroll
    for (int j = 0; j < 16; ++j) o[j] *= alpha;
#pragma unroll
    for (int g = 0; g < 4; ++g) {
#pragma unroll
      for (int j = 0; j < 16; ++j) {
        float p = __shfl(s[j], (tid & 60) | g, 64);
        const float4* vp = (const float4*)&Vs[g * 16 + j][cg * 16];
        float4 v0 = vp[0], v1 = vp[1], v2 = vp[2], v3 = vp[3];
        o[0]  = fmaf(p, v0.x, o[0]);  o[1]  = fmaf(p, v0.y, o[1]);
        o[2]  = fmaf(p, v0.z, o[2]);  o[3]  = fmaf(p, v0.w, o[3]);
        o[4]  = fmaf(p, v1.x, o[4]);  o[5]  = fmaf(p, v1.y, o[5]);
        o[6]  = fmaf(p, v1.z, o[6]);  o[7]  = fmaf(p, v1.w, o[7]);
        o[8]  = fmaf(p, v2.x, o[8]);  o[9]  = fmaf(p, v2.y, o[9]);
        o[10] = fmaf(p, v2.z, o[10]); o[11] = fmaf(p, v2.w, o[11]);
        o[12] = fmaf(p, v3.x, o[12]); o[13] = fmaf(p, v3.y, o[13]);
        o[14] = fmaf(p, v3.z, o[14]); o[15] = fmaf(p, v3.w, o[15]);
      }
    }
  }

  const float inv = 1.0f / l;
  const int u = tq >> 4, r = tq & 15;
  bf16* op = sa + ((size_t)(b * 2048 + h * 128 + u) * 1024 + r * 64 + cg * 16);
#pragma unroll
  for (int j = 0; j < 16; ++j) op[j] = __float2bfloat16(o[j] * inv);
}

extern "C" void kernel_launch(void* const* d_in, const int* in_sizes, int n_in,
                              void* d_out, int out_size, void* d_ws, size_t ws_size,
                              hipStream_t stream)
{
  const void* x_raw     = d_in[0];  // [4,2048,1024]
  const void* Wqkv_raw  = d_in[1];  // [1024,3072]
  const void* bqkv_raw  = d_in[2];  // [3072]
  const void* Wout_raw  = d_in[3];  // [1024,1024]
  const void* bout_raw  = d_in[4];  // [1024]

  char* ws = (char*)d_ws;
  // ws layout (bytes):
  int*  flag  = (int*)ws;                                    //   256 B
  bf16* xb    = (bf16*)(ws + 256);                           //  16 MiB (8192*1024)
  bf16* wqkvb = xb + (size_t)8192 * 1024;                    //   6 MiB (1024*3072)
  bf16* bqkvb = wqkvb + (size_t)1024 * 3072;                 //   6 KiB
  bf16* woutb = bqkvb + 4096;                                //   2 MiB (1024*1024)
  bf16* boutb = woutb + (size_t)1024 * 1024;                 //   2 KiB
  bf16* qkv   = boutb + 4096;                                //  48 MiB (8192*3072)
  bf16* sa    = qkv + (size_t)8192 * 3072;                   //  16 MiB (8192*1024)
  // total ~88.3 MiB

  detect_kernel<<<1, 64, 0, stream>>>((const unsigned int*)x_raw, flag);

  auto conv = [&](const void* src, bf16* dst, int n) {
    int n8 = n / 8;
    convert_kernel<<<(n8 + 255) / 256, 256, 0, stream>>>(src, dst, n8, flag);
  };
  conv(x_raw,    xb,    8192 * 1024);
  conv(Wqkv_raw, wqkvb, 1024 * 3072);
  conv(bqkv_raw, bqkvb, 3072);
  conv(Wout_raw, woutb, 1024 * 1024);
  conv(bout_raw, boutb, 1024);

  // 1) qkv = x @ W_qkv + b_qkv   (M=8192, N=3072, K=1024), store bf16
  gemm_bias<<<dim3(3072 / 64, 8192 / 64), 256, 0, stream>>>(
      xb, wqkvb, bqkvb, qkv, 8192, 3072, 1024, 0, flag);
  // 2) causal attention on permuted layout -> sa (bf16)
  attn<<<dim3(32, 64), 256, 0, stream>>>(qkv, sa);
  // 3) out = sa @ W_out + b_out  (M=8192, N=1024, K=1024), store per I/O dtype
  gemm_bias<<<dim3(1024 / 64, 8192 / 64), 256, 0, stream>>>(
      sa, woutb, boutb, d_out, 8192, 1024, 1024, 1, flag);
}

// Round 3
// 1217.450 us; speedup vs baseline: 2.8421x; 2.8421x over previous
//
#include <hip/hip_runtime.h>
#include <hip/hip_bf16.h>

using bf16 = __hip_bfloat16;

typedef __attribute__((ext_vector_type(8))) short short8;   // 8 x bf16 (4 VGPRs)
typedef __attribute__((ext_vector_type(4))) float f32x4;    // MFMA C/D

// MaskedMSA: B=4, S=2048, E=1024, HIDDEN=1024, HEADS=16
// Reference reshape mixes seq/hidden: with t=16u+r (u<128, r<16):
//   q[b,h,t,e] = qkv[b, 128h+u, 192r +   0 + e]
//   k[b,h,t,e] = qkv[b, 128h+u, 192r +  64 + e]
//   v[b,h,t,e] = qkv[b, 128h+u, 192r + 128 + e]
// Output: sa[b,h,t,e] -> out row 128h+u, col 64r+e. Causal mask on permuted t.
// For tile-aligned t = 64*tile + 16*sub + i (i<16): u = 4*tile + sub, r = i.

__device__ __forceinline__ void unpack2(unsigned int u, float& a, float& b) {
  union U { unsigned int i; float f; } x, y;
  x.i = u << 16; y.i = u & 0xffff0000u;
  a = x.f; b = y.f;
}

__device__ __forceinline__ unsigned short f2bf(float v) {
  bf16 h = __float2bfloat16(v);
  return *(unsigned short*)&h;
}

// ---- dtype detect: flag=1 if fp32 I/O, flag=0 if bf16 I/O.
__global__ void detect_kernel(const unsigned int* __restrict__ x, int* __restrict__ flag) {
  unsigned int w = x[threadIdx.x];
  unsigned int e = (w >> 7) & 0xFF;
  bool inband = (e >= 96 && e <= 133);
  unsigned long long m = __ballot(inband);
  if (threadIdx.x == 0) flag[0] = (__popcll(m) >= 48) ? 0 : 1;
}

// ---- convert n8*8 elements to bf16 (copy if already bf16)
__global__ __launch_bounds__(256) void convert_kernel(
    const void* __restrict__ src, bf16* __restrict__ dst, int n8,
    const int* __restrict__ flag) {
  int i = blockIdx.x * 256 + threadIdx.x;
  if (i >= n8) return;
  uint4 outv;
  if (*flag) {
    const float4* s = (const float4*)src + (size_t)i * 2;
    float4 a = s[0], b = s[1];
    outv.x = f2bf(a.x) | ((unsigned)f2bf(a.y) << 16);
    outv.y = f2bf(a.z) | ((unsigned)f2bf(a.w) << 16);
    outv.z = f2bf(b.x) | ((unsigned)f2bf(b.y) << 16);
    outv.w = f2bf(b.z) | ((unsigned)f2bf(b.w) << 16);
  } else {
    outv = ((const uint4*)src)[i];
  }
  ((uint4*)dst)[i] = outv;
}

// ---------------- GEMM: C[M,N] = A[M,K] @ B[K,N] + bias; bf16 in, fp32 accum.
__global__ __launch_bounds__(256) void gemm_bias(
    const bf16* __restrict__ A, const bf16* __restrict__ Bm,
    const bf16* __restrict__ bias, void* __restrict__ C,
    int M, int N, int K, int store_mode, const int* __restrict__ flag)
{
  __shared__ float As[16][68];
  __shared__ float Bs[16][68];
  const bool store_f32 = store_mode && (*flag != 0);
  const int tid = threadIdx.x;
  const int n0 = blockIdx.x * 64;
  const int m0 = blockIdx.y * 64;
  const int tx = tid & 15, ty = tid >> 4;
  const int arow = tid >> 2, acol = (tid & 3) << 2;
  const int brow = tid >> 4, bcol = (tid & 15) << 2;
  float acc[4][4] = {};
  for (int k0 = 0; k0 < K; k0 += 16) {
    __syncthreads();
    {
      const unsigned short* p = (const unsigned short*)A + (size_t)(m0 + arow) * K + (k0 + acol);
      uint2 v = *(const uint2*)p;
      float f0, f1, f2, f3; unpack2(v.x, f0, f1); unpack2(v.y, f2, f3);
      As[acol + 0][arow] = f0; As[acol + 1][arow] = f1;
      As[acol + 2][arow] = f2; As[acol + 3][arow] = f3;
    }
    {
      const unsigned short* p = (const unsigned short*)Bm + (size_t)(k0 + brow) * N + (n0 + bcol);
      uint2 v = *(const uint2*)p;
      float f0, f1, f2, f3; unpack2(v.x, f0, f1); unpack2(v.y, f2, f3);
      Bs[brow][bcol + 0] = f0; Bs[brow][bcol + 1] = f1;
      Bs[brow][bcol + 2] = f2; Bs[brow][bcol + 3] = f3;
    }
    __syncthreads();
#pragma unroll
    for (int kk = 0; kk < 16; ++kk) {
      const float4 av = *(const float4*)&As[kk][ty * 4];
      const float4 bv = *(const float4*)&Bs[kk][tx * 4];
      float a[4] = {av.x, av.y, av.z, av.w};
      float b[4] = {bv.x, bv.y, bv.z, bv.w};
#pragma unroll
      for (int i = 0; i < 4; ++i)
#pragma unroll
        for (int j = 0; j < 4; ++j)
          acc[i][j] = fmaf(a[i], b[j], acc[i][j]);
    }
  }
#pragma unroll
  for (int i = 0; i < 4; ++i) {
    const int mm = m0 + ty * 4 + i;
#pragma unroll
    for (int j = 0; j < 4; ++j) {
      const int nn = n0 + tx * 4 + j;
      float o = acc[i][j] + __bfloat162float(bias[nn]);
      if (store_f32) ((float*)C)[(size_t)mm * N + nn] = o;
      else           ((bf16*)C)[(size_t)mm * N + nn] = __float2bfloat16(o);
    }
  }
}

// ---------------- MFMA flash attention on the permuted layout.
// grid (32 q-tiles, 64 bh), 256 threads = 4 waves; wave w owns q rows
// [qt*64 + w*16, +16). Q/K fragments load straight from global (contiguous
// 16B per lane); V staged transposed in LDS; P C->A layout via wave-private
// LDS round-trip (m120-verified transform).
__global__ __launch_bounds__(256) void attn_mfma(const bf16* __restrict__ qkv,
                                                 bf16* __restrict__ sa)
{
  __shared__ short Vt[64 * 72];        // [d][key], stride 72 (bank-spread)
  __shared__ short Ps[4 * 16 * 72];    // per-wave [q_local][key], stride 72
  const int tid = threadIdx.x;
  const int qt = blockIdx.x;
  const int bh = blockIdx.y;
  const size_t base = (size_t)bh * 393216;  // (bh*128) * 3072
  const int wave = tid >> 6;
  const int lane = tid & 63;
  const int l15 = lane & 15;
  const int l4 = lane >> 4;                 // quad 0..3
  const unsigned short* qk = (const unsigned short*)qkv;
  const float scale = 0.022097086912079608f;  // (2*1024)^-0.5

  // Q fragments, held for the whole kernel. A[m=l15][k=l4*8+j], k-slabs d0..31/d32..63
  short8 qf0, qf1;
  {
    const unsigned short* p = qk + base + (size_t)(qt * 4 + wave) * 3072 + l15 * 192 + l4 * 8;
    qf0 = *(const short8*)p;
    qf1 = *(const short8*)(p + 32);
  }

  f32x4 o[4] = {};         // O acc, jn = d-tile; reg = q row (C layout)
  float mrow[4], lrow[4];
#pragma unroll
  for (int r = 0; r < 4; ++r) { mrow[r] = -__builtin_inff(); lrow[r] = 0.f; }

  short* psw = Ps + wave * (16 * 72);

  for (int kt = 0; kt <= qt; ++kt) {
    __syncthreads();  // Vt reads of previous iteration complete
    // stage V transposed: thread handles key=tid&63, d-vectors (tid>>6) and (tid>>6)+4
    {
      const int key = tid & 63;
      const unsigned short* pv =
          qk + base + (size_t)(kt * 4 + (key >> 4)) * 3072 + (key & 15) * 192 + 128;
#pragma unroll
      for (int it = 0; it < 2; ++it) {
        const int dvec = (tid >> 6) + it * 4;
        short8 v = *(const short8*)(pv + dvec * 8);
#pragma unroll
        for (int jj = 0; jj < 8; ++jj) Vt[(dvec * 8 + jj) * 72 + key] = v[jj];
      }
    }
    __syncthreads();  // Vt ready

    // ---- S = Q K^T (16 q x 64 key per wave)
    f32x4 sc[4];
#pragma unroll
    for (int jn = 0; jn < 4; ++jn) {
      const unsigned short* pk =
          qk + base + (size_t)(kt * 4 + jn) * 3072 + l15 * 192 + 64 + l4 * 8;
      short8 k0 = *(const short8*)pk;
      short8 k1 = *(const short8*)(pk + 32);
      f32x4 c = {};
      c = __builtin_amdgcn_mfma_f32_16x16x32_bf16(qf0, k0, c, 0, 0, 0);
      c = __builtin_amdgcn_mfma_f32_16x16x32_bf16(qf1, k1, c, 0, 0, 0);
      sc[jn] = c;
    }

    // ---- scale + causal mask + online softmax (row = l4*4+r, spread over 16 lanes)
    const bool diag = (kt == qt);
#pragma unroll
    for (int r = 0; r < 4; ++r) {
      const int qloc = l4 * 4 + r;  // q row within wave tile
      float mx = -__builtin_inff();
#pragma unroll
      for (int jn = 0; jn < 4; ++jn) {
        float v = sc[jn][r] * scale;
        if (diag && (jn * 16 + l15 > wave * 16 + qloc)) v = -__builtin_inff();
        sc[jn][r] = v;
        mx = fmaxf(mx, v);
      }
      mx = fmaxf(mx, __shfl_xor(mx, 1, 64));
      mx = fmaxf(mx, __shfl_xor(mx, 2, 64));
      mx = fmaxf(mx, __shfl_xor(mx, 4, 64));
      mx = fmaxf(mx, __shfl_xor(mx, 8, 64));
      const float m_new = fmaxf(mrow[r], mx);
      const float alpha = __expf(mrow[r] - m_new);
      mrow[r] = m_new;
      float sum = 0.f;
#pragma unroll
      for (int jn = 0; jn < 4; ++jn) {
        float p = __expf(sc[jn][r] - m_new);
        sc[jn][r] = p;
        sum += p;
      }
      sum += __shfl_xor(sum, 1, 64);
      sum += __shfl_xor(sum, 2, 64);
      sum += __shfl_xor(sum, 4, 64);
      sum += __shfl_xor(sum, 8, 64);
      lrow[r] = lrow[r] * alpha + sum;
#pragma unroll
      for (int jn = 0; jn < 4; ++jn) o[jn][r] *= alpha;
    }

    // ---- P: C layout -> A layout via wave-private LDS
#pragma unroll
    for (int r = 0; r < 4; ++r)
#pragma unroll
      for (int jn = 0; jn < 4; ++jn)
        psw[(l4 * 4 + r) * 72 + jn * 16 + l15] = (short)f2bf(sc[jn][r]);
    __syncthreads();  // conservative: also orders wave-private write->read

    short8 pf0 = *(const short8*)(psw + l15 * 72 + l4 * 8);
    short8 pf1 = *(const short8*)(psw + l15 * 72 + 32 + l4 * 8);

    // ---- O += P V  (B frag from Vt: B[n=d=jn*16+l15][k=key])
#pragma unroll
    for (int jn = 0; jn < 4; ++jn) {
      const short* pvt = Vt + (jn * 16 + l15) * 72 + l4 * 8;
      short8 v0 = *(const short8*)pvt;
      short8 v1 = *(const short8*)(pvt + 32);
      o[jn] = __builtin_amdgcn_mfma_f32_16x16x32_bf16(pf0, v0, o[jn], 0, 0, 0);
      o[jn] = __builtin_amdgcn_mfma_f32_16x16x32_bf16(pf1, v1, o[jn], 0, 0, 0);
    }
  }

  // ---- epilogue: O/l -> sa (row bh*128 + qt*4 + wave, col qloc*64 + d)
  unsigned short* so = (unsigned short*)sa + (size_t)(bh * 128 + qt * 4 + wave) * 1024;
#pragma unroll
  for (int r = 0; r < 4; ++r) {
    const float inv = 1.0f / lrow[r];
    const int qloc = l4 * 4 + r;
#pragma unroll
    for (int jn = 0; jn < 4; ++jn)
      so[qloc * 64 + jn * 16 + l15] = f2bf(o[jn][r] * inv);
  }
}

extern "C" void kernel_launch(void* const* d_in, const int* in_sizes, int n_in,
                              void* d_out, int out_size, void* d_ws, size_t ws_size,
                              hipStream_t stream)
{
  const void* x_raw     = d_in[0];  // [4,2048,1024]
  const void* Wqkv_raw  = d_in[1];  // [1024,3072]
  const void* bqkv_raw  = d_in[2];  // [3072]
  const void* Wout_raw  = d_in[3];  // [1024,1024]
  const void* bout_raw  = d_in[4];  // [1024]

  char* ws = (char*)d_ws;
  int*  flag  = (int*)ws;                                    //   256 B
  bf16* xb    = (bf16*)(ws + 256);                           //  16 MiB
  bf16* wqkvb = xb + (size_t)8192 * 1024;                    //   6 MiB
  bf16* bqkvb = wqkvb + (size_t)1024 * 3072;                 //   6 KiB
  bf16* woutb = bqkvb + 4096;                                //   2 MiB
  bf16* boutb = woutb + (size_t)1024 * 1024;                 //   2 KiB
  bf16* qkv   = boutb + 4096;                                //  48 MiB
  bf16* sa    = qkv + (size_t)8192 * 3072;                   //  16 MiB

  detect_kernel<<<1, 64, 0, stream>>>((const unsigned int*)x_raw, flag);

  auto conv = [&](const void* src, bf16* dst, int n) {
    int n8 = n / 8;
    convert_kernel<<<(n8 + 255) / 256, 256, 0, stream>>>(src, dst, n8, flag);
  };
  conv(x_raw,    xb,    8192 * 1024);
  conv(Wqkv_raw, wqkvb, 1024 * 3072);
  conv(bqkv_raw, bqkvb, 3072);
  conv(Wout_raw, woutb, 1024 * 1024);
  conv(bout_raw, boutb, 1024);

  // 1) qkv = x @ W_qkv + b_qkv   (M=8192, N=3072, K=1024)
  gemm_bias<<<dim3(3072 / 64, 8192 / 64), 256, 0, stream>>>(
      xb, wqkvb, bqkvb, qkv, 8192, 3072, 1024, 0, flag);
  // 2) MFMA flash attention on permuted layout -> sa (bf16)
  attn_mfma<<<dim3(32, 64), 256, 0, stream>>>(qkv, sa);
  // 3) out = sa @ W_out + b_out  (M=8192, N=1024, K=1024)
  gemm_bias<<<dim3(1024 / 64, 8192 / 64), 256, 0, stream>>>(
      sa, woutb, boutb, d_out, 8192, 1024, 1024, 1, flag);
}

// Round 4
// 510.525 us; speedup vs baseline: 6.7775x; 2.3847x over previous
//
#include <hip/hip_runtime.h>
#include <hip/hip_bf16.h>

using bf16 = __hip_bfloat16;

typedef __attribute__((ext_vector_type(8))) short short8;   // 8 x bf16 (4 VGPRs)
typedef __attribute__((ext_vector_type(4))) float f32x4;    // MFMA C/D

// MaskedMSA: B=4, S=2048, E=1024, HIDDEN=1024, HEADS=16
// Reference reshape mixes seq/hidden: with t=16u+r (u<128, r<16):
//   q[b,h,t,e] = qkv[b, 128h+u, 192r +   0 + e]
//   k[b,h,t,e] = qkv[b, 128h+u, 192r +  64 + e]
//   v[b,h,t,e] = qkv[b, 128h+u, 192r + 128 + e]
// Output: sa[b,h,t,e] -> out row 128h+u, col 64r+e. Causal mask on permuted t.

__device__ __forceinline__ void unpack2(unsigned int u, float& a, float& b) {
  union U { unsigned int i; float f; } x, y;
  x.i = u << 16; y.i = u & 0xffff0000u;
  a = x.f; b = y.f;
}

__device__ __forceinline__ unsigned short f2bf(float v) {
  bf16 h = __float2bfloat16(v);
  return *(unsigned short*)&h;
}

// async global->LDS, 16B per lane; LDS dest = wave-uniform base + lane*16.
__device__ __forceinline__ void gload_lds16(const void* g, void* lds) {
  __builtin_amdgcn_global_load_lds(
      (const __attribute__((address_space(1))) unsigned int*)(g),
      (__attribute__((address_space(3))) unsigned int*)(lds), 16, 0, 0);
}

// ---- dtype detect: flag=1 if fp32 I/O, flag=0 if bf16 I/O.
__global__ void detect_kernel(const unsigned int* __restrict__ x, int* __restrict__ flag) {
  unsigned int w = x[threadIdx.x];
  unsigned int e = (w >> 7) & 0xFF;
  bool inband = (e >= 96 && e <= 133);
  unsigned long long m = __ballot(inband);
  if (threadIdx.x == 0) flag[0] = (__popcll(m) >= 48) ? 0 : 1;
}

// ---- convert n8*8 elements to bf16 (copy if already bf16)
__global__ __launch_bounds__(256) void convert_kernel(
    const void* __restrict__ src, bf16* __restrict__ dst, int n8,
    const int* __restrict__ flag) {
  int i = blockIdx.x * 256 + threadIdx.x;
  if (i >= n8) return;
  uint4 outv;
  if (*flag) {
    const float4* s = (const float4*)src + (size_t)i * 2;
    float4 a = s[0], b = s[1];
    outv.x = f2bf(a.x) | ((unsigned)f2bf(a.y) << 16);
    outv.y = f2bf(a.z) | ((unsigned)f2bf(a.w) << 16);
    outv.z = f2bf(b.x) | ((unsigned)f2bf(b.y) << 16);
    outv.w = f2bf(b.z) | ((unsigned)f2bf(b.w) << 16);
  } else {
    outv = ((const uint4*)src)[i];
  }
  ((uint4*)dst)[i] = outv;
}

// ---- transpose src[R][C] -> dst[C][R], converting to bf16 per flag
__global__ __launch_bounds__(256) void transpose_bf16(
    const void* __restrict__ src, bf16* __restrict__ dst, int R, int Cc,
    const int* __restrict__ flag) {
  __shared__ float tile[32][33];
  const int c0 = blockIdx.x * 32, r0 = blockIdx.y * 32;
  const int tx = threadIdx.x & 31, ty = threadIdx.x >> 5;  // 32 x 8
  const bool f32 = (*flag != 0);
#pragma unroll
  for (int it = 0; it < 4; ++it) {
    int r = ty + it * 8;
    float v;
    if (f32) v = ((const float*)src)[(size_t)(r0 + r) * Cc + c0 + tx];
    else     v = __bfloat162float(((const bf16*)src)[(size_t)(r0 + r) * Cc + c0 + tx]);
    tile[r][tx] = v;
  }
  __syncthreads();
#pragma unroll
  for (int it = 0; it < 4; ++it) {
    int r = ty + it * 8;   // row in dst tile (= src col)
    dst[(size_t)(c0 + r) * R + r0 + tx] = __float2bfloat16(tile[tx][r]);
  }
}

// ---------------- MFMA GEMM (m97 pattern): C[M,N] = A[M,K] @ BT[N,K]^T + bias
// 128x128 tile, BK=32, 4 waves, 4x4 16x16x32 fragments/wave, global_load_lds.
__global__ __launch_bounds__(256) void gemm_mfma(
    const bf16* __restrict__ A, const bf16* __restrict__ BT,
    const bf16* __restrict__ bias, void* __restrict__ C,
    int M, int N, int K, int store_mode, const int* __restrict__ flag)
{
  __shared__ alignas(16) unsigned short As[128 * 32];  // [m][k] contiguous
  __shared__ alignas(16) unsigned short Bs[128 * 32];  // [n][k] contiguous
  const bool store_f32 = store_mode && (*flag != 0);
  const int tid = threadIdx.x;
  const int wave = tid >> 6, lane = tid & 63;
  const int l15 = lane & 15, l4 = lane >> 4;
  const int m0 = blockIdx.y * 128, n0 = blockIdx.x * 128;
  const int wm = (wave & 1) * 64, wn = (wave >> 1) * 64;

  // staging: wave handles tile rows [32*wave, 32*wave+32); lane -> (row, kvec)
  const int srow = wave * 32 + (lane >> 2);
  const int skv = (lane & 3) * 8;
  const bf16* ga = A + (size_t)(m0 + srow) * K + skv;
  const bf16* gb = BT + (size_t)(n0 + srow) * K + skv;
  unsigned short* la = As + (wave * 32) * 32;  // wave-uniform LDS base
  unsigned short* lb = Bs + (wave * 32) * 32;

  f32x4 acc[4][4] = {};

  for (int k0 = 0; k0 < K; k0 += 32) {
    __syncthreads();           // previous iter's fragment reads done
    gload_lds16(ga, la);
    gload_lds16(ga + (size_t)16 * K, la + 16 * 32);
    gload_lds16(gb, lb);
    gload_lds16(gb + (size_t)16 * K, lb + 16 * 32);
    ga += 32; gb += 32;
    __syncthreads();           // drains vmcnt -> LDS visible

    short8 af[4], bfr[4];
#pragma unroll
    for (int i = 0; i < 4; ++i) {
      af[i]  = *(const short8*)(As + (wm + i * 16 + l15) * 32 + l4 * 8);
      bfr[i] = *(const short8*)(Bs + (wn + i * 16 + l15) * 32 + l4 * 8);
    }
#pragma unroll
    for (int i = 0; i < 4; ++i)
#pragma unroll
      for (int j = 0; j < 4; ++j)
        acc[i][j] = __builtin_amdgcn_mfma_f32_16x16x32_bf16(af[i], bfr[j], acc[i][j], 0, 0, 0);
  }

  // epilogue: C row = wm+i*16+l4*4+r, col = wn+j*16+l15
#pragma unroll
  for (int j = 0; j < 4; ++j) {
    const int n = n0 + wn + j * 16 + l15;
    const float bv = __bfloat162float(bias[n]);
#pragma unroll
    for (int i = 0; i < 4; ++i) {
#pragma unroll
      for (int r = 0; r < 4; ++r) {
        const int mrow = m0 + wm + i * 16 + l4 * 4 + r;
        const float v = acc[i][j][r] + bv;
        if (store_f32) ((float*)C)[(size_t)mrow * N + n] = v;
        else           ((bf16*)C)[(size_t)mrow * N + n] = __float2bfloat16(v);
      }
    }
  }
}

// ---------------- MFMA flash attention on the permuted layout (unchanged R3).
__global__ __launch_bounds__(256) void attn_mfma(const bf16* __restrict__ qkv,
                                                 bf16* __restrict__ sa)
{
  __shared__ short Vt[64 * 72];        // [d][key], stride 72
  __shared__ short Ps[4 * 16 * 72];    // per-wave [q_local][key], stride 72
  const int tid = threadIdx.x;
  const int qt = blockIdx.x;
  const int bh = blockIdx.y;
  const size_t base = (size_t)bh * 393216;  // (bh*128) * 3072
  const int wave = tid >> 6;
  const int lane = tid & 63;
  const int l15 = lane & 15;
  const int l4 = lane >> 4;
  const unsigned short* qk = (const unsigned short*)qkv;
  const float scale = 0.022097086912079608f;  // (2*1024)^-0.5

  short8 qf0, qf1;
  {
    const unsigned short* p = qk + base + (size_t)(qt * 4 + wave) * 3072 + l15 * 192 + l4 * 8;
    qf0 = *(const short8*)p;
    qf1 = *(const short8*)(p + 32);
  }

  f32x4 o[4] = {};
  float mrow[4], lrow[4];
#pragma unroll
  for (int r = 0; r < 4; ++r) { mrow[r] = -__builtin_inff(); lrow[r] = 0.f; }

  short* psw = Ps + wave * (16 * 72);

  for (int kt = 0; kt <= qt; ++kt) {
    __syncthreads();
    {
      const int key = tid & 63;
      const unsigned short* pv =
          qk + base + (size_t)(kt * 4 + (key >> 4)) * 3072 + (key & 15) * 192 + 128;
#pragma unroll
      for (int it = 0; it < 2; ++it) {
        const int dvec = (tid >> 6) + it * 4;
        short8 v = *(const short8*)(pv + dvec * 8);
#pragma unroll
        for (int jj = 0; jj < 8; ++jj) Vt[(dvec * 8 + jj) * 72 + key] = v[jj];
      }
    }
    __syncthreads();

    f32x4 sc[4];
#pragma unroll
    for (int jn = 0; jn < 4; ++jn) {
      const unsigned short* pk =
          qk + base + (size_t)(kt * 4 + jn) * 3072 + l15 * 192 + 64 + l4 * 8;
      short8 k0 = *(const short8*)pk;
      short8 k1 = *(const short8*)(pk + 32);
      f32x4 c = {};
      c = __builtin_amdgcn_mfma_f32_16x16x32_bf16(qf0, k0, c, 0, 0, 0);
      c = __builtin_amdgcn_mfma_f32_16x16x32_bf16(qf1, k1, c, 0, 0, 0);
      sc[jn] = c;
    }

    const bool diag = (kt == qt);
#pragma unroll
    for (int r = 0; r < 4; ++r) {
      const int qloc = l4 * 4 + r;
      float mx = -__builtin_inff();
#pragma unroll
      for (int jn = 0; jn < 4; ++jn) {
        float v = sc[jn][r] * scale;
        if (diag && (jn * 16 + l15 > wave * 16 + qloc)) v = -__builtin_inff();
        sc[jn][r] = v;
        mx = fmaxf(mx, v);
      }
      mx = fmaxf(mx, __shfl_xor(mx, 1, 64));
      mx = fmaxf(mx, __shfl_xor(mx, 2, 64));
      mx = fmaxf(mx, __shfl_xor(mx, 4, 64));
      mx = fmaxf(mx, __shfl_xor(mx, 8, 64));
      const float m_new = fmaxf(mrow[r], mx);
      const float alpha = __expf(mrow[r] - m_new);
      mrow[r] = m_new;
      float sum = 0.f;
#pragma unroll
      for (int jn = 0; jn < 4; ++jn) {
        float p = __expf(sc[jn][r] - m_new);
        sc[jn][r] = p;
        sum += p;
      }
      sum += __shfl_xor(sum, 1, 64);
      sum += __shfl_xor(sum, 2, 64);
      sum += __shfl_xor(sum, 4, 64);
      sum += __shfl_xor(sum, 8, 64);
      lrow[r] = lrow[r] * alpha + sum;
#pragma unroll
      for (int jn = 0; jn < 4; ++jn) o[jn][r] *= alpha;
    }

#pragma unroll
    for (int r = 0; r < 4; ++r)
#pragma unroll
      for (int jn = 0; jn < 4; ++jn)
        psw[(l4 * 4 + r) * 72 + jn * 16 + l15] = (short)f2bf(sc[jn][r]);
    __syncthreads();

    short8 pf0 = *(const short8*)(psw + l15 * 72 + l4 * 8);
    short8 pf1 = *(const short8*)(psw + l15 * 72 + 32 + l4 * 8);

#pragma unroll
    for (int jn = 0; jn < 4; ++jn) {
      const short* pvt = Vt + (jn * 16 + l15) * 72 + l4 * 8;
      short8 v0 = *(const short8*)pvt;
      short8 v1 = *(const short8*)(pvt + 32);
      o[jn] = __builtin_amdgcn_mfma_f32_16x16x32_bf16(pf0, v0, o[jn], 0, 0, 0);
      o[jn] = __builtin_amdgcn_mfma_f32_16x16x32_bf16(pf1, v1, o[jn], 0, 0, 0);
    }
  }

  unsigned short* so = (unsigned short*)sa + (size_t)(bh * 128 + qt * 4 + wave) * 1024;
#pragma unroll
  for (int r = 0; r < 4; ++r) {
    const float inv = 1.0f / lrow[r];
    const int qloc = l4 * 4 + r;
#pragma unroll
    for (int jn = 0; jn < 4; ++jn)
      so[qloc * 64 + jn * 16 + l15] = f2bf(o[jn][r] * inv);
  }
}

extern "C" void kernel_launch(void* const* d_in, const int* in_sizes, int n_in,
                              void* d_out, int out_size, void* d_ws, size_t ws_size,
                              hipStream_t stream)
{
  const void* x_raw    = d_in[0];  // [4,2048,1024]
  const void* Wqkv_raw = d_in[1];  // [1024,3072]
  const void* bqkv_raw = d_in[2];  // [3072]
  const void* Wout_raw = d_in[3];  // [1024,1024]
  const void* bout_raw = d_in[4];  // [1024]

  char* ws = (char*)d_ws;
  int*  flag   = (int*)ws;                                  //   256 B
  bf16* xb     = (bf16*)(ws + 256);                         //  16 MiB (8192*1024)
  bf16* wqkvT  = xb + (size_t)8192 * 1024;                  //   6 MiB (3072*1024, [N][K])
  bf16* bqkvb  = wqkvT + (size_t)3072 * 1024;               //   6 KiB
  bf16* woutT  = bqkvb + 4096;                              //   2 MiB (1024*1024, [N][K])
  bf16* boutb  = woutT + (size_t)1024 * 1024;               //   2 KiB
  bf16* qkv    = boutb + 4096;                              //  48 MiB (8192*3072)
  bf16* sa     = qkv + (size_t)8192 * 3072;                 //  16 MiB (8192*1024)

  detect_kernel<<<1, 64, 0, stream>>>((const unsigned int*)x_raw, flag);

  auto conv = [&](const void* src, bf16* dst, int n) {
    int n8 = n / 8;
    convert_kernel<<<(n8 + 255) / 256, 256, 0, stream>>>(src, dst, n8, flag);
  };
  conv(x_raw, xb, 8192 * 1024);
  conv(bqkv_raw, bqkvb, 3072);
  conv(bout_raw, boutb, 1024);
  // weights: convert + transpose to [N][K]
  transpose_bf16<<<dim3(3072 / 32, 1024 / 32), 256, 0, stream>>>(Wqkv_raw, wqkvT, 1024, 3072, flag);
  transpose_bf16<<<dim3(1024 / 32, 1024 / 32), 256, 0, stream>>>(Wout_raw, woutT, 1024, 1024, flag);

  // 1) qkv = x @ W_qkv + b_qkv   (M=8192, N=3072, K=1024)
  gemm_mfma<<<dim3(3072 / 128, 8192 / 128), 256, 0, stream>>>(
      xb, wqkvT, bqkvb, qkv, 8192, 3072, 1024, 0, flag);
  // 2) MFMA flash attention on permuted layout -> sa (bf16)
  attn_mfma<<<dim3(32, 64), 256, 0, stream>>>(qkv, sa);
  // 3) out = sa @ W_out + b_out  (M=8192, N=1024, K=1024)
  gemm_mfma<<<dim3(1024 / 128, 8192 / 128), 256, 0, stream>>>(
      sa, woutT, boutb, d_out, 8192, 1024, 1024, 1, flag);
}

// Round 5
// 374.396 us; speedup vs baseline: 9.2418x; 1.3636x over previous
//
#include <hip/hip_runtime.h>
#include <hip/hip_bf16.h>

using bf16 = __hip_bfloat16;

typedef __attribute__((ext_vector_type(8))) short short8;   // 8 x bf16 (4 VGPRs)
typedef __attribute__((ext_vector_type(4))) float f32x4;    // MFMA C/D

// MaskedMSA: B=4, S=2048, E=1024, HIDDEN=1024, HEADS=16
// Reference reshape mixes seq/hidden: with t=16u+r (u<128, r<16):
//   q[b,h,t,e] = qkv[b, 128h+u, 192r +   0 + e]
//   k[b,h,t,e] = qkv[b, 128h+u, 192r +  64 + e]
//   v[b,h,t,e] = qkv[b, 128h+u, 192r + 128 + e]
// Output: sa[b,h,t,e] -> out row 128h+u, col 64r+e. Causal mask on permuted t.

__device__ __forceinline__ void unpack2(unsigned int u, float& a, float& b) {
  union U { unsigned int i; float f; } x, y;
  x.i = u << 16; y.i = u & 0xffff0000u;
  a = x.f; b = y.f;
}

__device__ __forceinline__ unsigned short f2bf(float v) {
  bf16 h = __float2bfloat16(v);
  return *(unsigned short*)&h;
}

// async global->LDS, 16B per lane; LDS dest = wave-uniform base + lane*16.
__device__ __forceinline__ void gload_lds16(const void* g, void* lds) {
  __builtin_amdgcn_global_load_lds(
      (const __attribute__((address_space(1))) unsigned int*)(g),
      (__attribute__((address_space(3))) unsigned int*)(lds), 16, 0, 0);
}

// ---- dtype detect: flag=1 if fp32 I/O, flag=0 if bf16 I/O.
__global__ void detect_kernel(const unsigned int* __restrict__ x, int* __restrict__ flag) {
  unsigned int w = x[threadIdx.x];
  unsigned int e = (w >> 7) & 0xFF;
  bool inband = (e >= 96 && e <= 133);
  unsigned long long m = __ballot(inband);
  if (threadIdx.x == 0) flag[0] = (__popcll(m) >= 48) ? 0 : 1;
}

// ---- convert n8*8 elements to bf16 (copy if already bf16)
__global__ __launch_bounds__(256) void convert_kernel(
    const void* __restrict__ src, bf16* __restrict__ dst, int n8,
    const int* __restrict__ flag) {
  int i = blockIdx.x * 256 + threadIdx.x;
  if (i >= n8) return;
  uint4 outv;
  if (*flag) {
    const float4* s = (const float4*)src + (size_t)i * 2;
    float4 a = s[0], b = s[1];
    outv.x = f2bf(a.x) | ((unsigned)f2bf(a.y) << 16);
    outv.y = f2bf(a.z) | ((unsigned)f2bf(a.w) << 16);
    outv.z = f2bf(b.x) | ((unsigned)f2bf(b.y) << 16);
    outv.w = f2bf(b.z) | ((unsigned)f2bf(b.w) << 16);
  } else {
    outv = ((const uint4*)src)[i];
  }
  ((uint4*)dst)[i] = outv;
}

// ---- transpose src[R][C] -> dst[C][R], converting to bf16 per flag
__global__ __launch_bounds__(256) void transpose_bf16(
    const void* __restrict__ src, bf16* __restrict__ dst, int R, int Cc,
    const int* __restrict__ flag) {
  __shared__ float tile[32][33];
  const int c0 = blockIdx.x * 32, r0 = blockIdx.y * 32;
  const int tx = threadIdx.x & 31, ty = threadIdx.x >> 5;  // 32 x 8
  const bool f32 = (*flag != 0);
#pragma unroll
  for (int it = 0; it < 4; ++it) {
    int r = ty + it * 8;
    float v;
    if (f32) v = ((const float*)src)[(size_t)(r0 + r) * Cc + c0 + tx];
    else     v = __bfloat162float(((const bf16*)src)[(size_t)(r0 + r) * Cc + c0 + tx]);
    tile[r][tx] = v;
  }
  __syncthreads();
#pragma unroll
  for (int it = 0; it < 4; ++it) {
    int r = ty + it * 8;   // row in dst tile (= src col)
    dst[(size_t)(c0 + r) * R + r0 + tx] = __float2bfloat16(tile[tx][r]);
  }
}

// ---------------- MFMA GEMM (m97 pattern): C[M,N] = A[M,K] @ BT[N,K]^T + bias
__global__ __launch_bounds__(256) void gemm_mfma(
    const bf16* __restrict__ A, const bf16* __restrict__ BT,
    const bf16* __restrict__ bias, void* __restrict__ C,
    int M, int N, int K, int store_mode, const int* __restrict__ flag)
{
  __shared__ alignas(16) unsigned short As[128 * 32];  // [m][k] contiguous
  __shared__ alignas(16) unsigned short Bs[128 * 32];  // [n][k] contiguous
  const bool store_f32 = store_mode && (*flag != 0);
  const int tid = threadIdx.x;
  const int wave = tid >> 6, lane = tid & 63;
  const int l15 = lane & 15, l4 = lane >> 4;
  const int m0 = blockIdx.y * 128, n0 = blockIdx.x * 128;
  const int wm = (wave & 1) * 64, wn = (wave >> 1) * 64;

  const int srow = wave * 32 + (lane >> 2);
  const int skv = (lane & 3) * 8;
  const bf16* ga = A + (size_t)(m0 + srow) * K + skv;
  const bf16* gb = BT + (size_t)(n0 + srow) * K + skv;
  unsigned short* la = As + (wave * 32) * 32;
  unsigned short* lb = Bs + (wave * 32) * 32;

  f32x4 acc[4][4] = {};

  for (int k0 = 0; k0 < K; k0 += 32) {
    __syncthreads();
    gload_lds16(ga, la);
    gload_lds16(ga + (size_t)16 * K, la + 16 * 32);
    gload_lds16(gb, lb);
    gload_lds16(gb + (size_t)16 * K, lb + 16 * 32);
    ga += 32; gb += 32;
    __syncthreads();

    short8 af[4], bfr[4];
#pragma unroll
    for (int i = 0; i < 4; ++i) {
      af[i]  = *(const short8*)(As + (wm + i * 16 + l15) * 32 + l4 * 8);
      bfr[i] = *(const short8*)(Bs + (wn + i * 16 + l15) * 32 + l4 * 8);
    }
#pragma unroll
    for (int i = 0; i < 4; ++i)
#pragma unroll
      for (int j = 0; j < 4; ++j)
        acc[i][j] = __builtin_amdgcn_mfma_f32_16x16x32_bf16(af[i], bfr[j], acc[i][j], 0, 0, 0);
  }

#pragma unroll
  for (int j = 0; j < 4; ++j) {
    const int n = n0 + wn + j * 16 + l15;
    const float bv = __bfloat162float(bias[n]);
#pragma unroll
    for (int i = 0; i < 4; ++i) {
#pragma unroll
      for (int r = 0; r < 4; ++r) {
        const int mrow = m0 + wm + i * 16 + l4 * 4 + r;
        const float v = acc[i][j][r] + bv;
        if (store_f32) ((float*)C)[(size_t)mrow * N + n] = v;
        else           ((bf16*)C)[(size_t)mrow * N + n] = __float2bfloat16(v);
      }
    }
  }
}

// ---------------- MFMA flash attention on the permuted layout.
// grid (64 bh, 32), qt = 31 - blockIdx.y  => LPT: heaviest blocks dispatch first.
// V software-pipelined in registers; 2 barriers/iter (P buffer is wave-private,
// same-wave DS ordering makes its round-trip barrier-free); exp2-domain softmax.
__global__ __launch_bounds__(256, 4) void attn_mfma(const bf16* __restrict__ qkv,
                                                    bf16* __restrict__ sa)
{
  __shared__ short Vt[64 * 72];        // [d][key], stride 72
  __shared__ short Ps[4 * 16 * 72];    // per-wave [q_local][key], stride 72
  const int tid = threadIdx.x;
  const int qt = 31 - blockIdx.y;      // LPT order
  const int bh = blockIdx.x;
  const size_t base = (size_t)bh * 393216;  // (bh*128) * 3072
  const int wave = tid >> 6;
  const int lane = tid & 63;
  const int l15 = lane & 15;
  const int l4 = lane >> 4;
  const unsigned short* qk = (const unsigned short*)qkv;
  // scale * log2(e): softmax in exp2 domain
  const float cexp = 0.022097086912079608f * 1.4426950408889634f;

  short8 qf0, qf1;
  {
    const unsigned short* p = qk + base + (size_t)(qt * 4 + wave) * 3072 + l15 * 192 + l4 * 8;
    qf0 = *(const short8*)p;
    qf1 = *(const short8*)(p + 32);
  }

  // V pipeline: this thread owns key=tid&63, d-vectors dv0 and dv0+4
  const int key = tid & 63;
  const int dv0 = tid >> 6;
  const unsigned short* vbase =
      qk + base + (size_t)(key >> 4) * 3072 + (key & 15) * 192 + 128;
  short8 vn0 = *(const short8*)(vbase + dv0 * 8);          // kt=0 prefetch
  short8 vn1 = *(const short8*)(vbase + (dv0 + 4) * 8);

  f32x4 o[4] = {};
  float mrow[4], lrow[4];
#pragma unroll
  for (int r = 0; r < 4; ++r) { mrow[r] = -__builtin_inff(); lrow[r] = 0.f; }

  short* psw = Ps + wave * (16 * 72);

  for (int kt = 0; kt <= qt; ++kt) {
    __syncthreads();                       // prior PV reads of Vt done
    {
      short8 vc0 = vn0, vc1 = vn1;
#pragma unroll
      for (int jj = 0; jj < 8; ++jj) {
        Vt[(dv0 * 8 + jj) * 72 + key] = vc0[jj];
        Vt[((dv0 + 4) * 8 + jj) * 72 + key] = vc1[jj];
      }
    }
    if (kt < qt) {                         // prefetch next V during this iter
      const unsigned short* pv = vbase + (size_t)(kt + 1) * 12288;  // 4*3072
      vn0 = *(const short8*)(pv + dv0 * 8);
      vn1 = *(const short8*)(pv + (dv0 + 4) * 8);
    }
    __syncthreads();                       // Vt ready

    f32x4 sc[4];
#pragma unroll
    for (int jn = 0; jn < 4; ++jn) {
      const unsigned short* pk =
          qk + base + (size_t)(kt * 4 + jn) * 3072 + l15 * 192 + 64 + l4 * 8;
      short8 k0 = *(const short8*)pk;
      short8 k1 = *(const short8*)(pk + 32);
      f32x4 c = {};
      c = __builtin_amdgcn_mfma_f32_16x16x32_bf16(qf0, k0, c, 0, 0, 0);
      c = __builtin_amdgcn_mfma_f32_16x16x32_bf16(qf1, k1, c, 0, 0, 0);
      sc[jn] = c;
    }

    const bool diag = (kt == qt);
#pragma unroll
    for (int r = 0; r < 4; ++r) {
      const int qloc = l4 * 4 + r;
      float mx = -__builtin_inff();
#pragma unroll
      for (int jn = 0; jn < 4; ++jn) {
        float v = sc[jn][r] * cexp;        // log2-domain score
        if (diag && (jn * 16 + l15 > wave * 16 + qloc)) v = -__builtin_inff();
        sc[jn][r] = v;
        mx = fmaxf(mx, v);
      }
      mx = fmaxf(mx, __shfl_xor(mx, 1, 64));
      mx = fmaxf(mx, __shfl_xor(mx, 2, 64));
      mx = fmaxf(mx, __shfl_xor(mx, 4, 64));
      mx = fmaxf(mx, __shfl_xor(mx, 8, 64));
      const float m_new = fmaxf(mrow[r], mx);
      const float alpha = exp2f(mrow[r] - m_new);
      mrow[r] = m_new;
      float sum = 0.f;
#pragma unroll
      for (int jn = 0; jn < 4; ++jn) {
        float p = exp2f(sc[jn][r] - m_new);
        sc[jn][r] = p;
        sum += p;
      }
      sum += __shfl_xor(sum, 1, 64);
      sum += __shfl_xor(sum, 2, 64);
      sum += __shfl_xor(sum, 4, 64);
      sum += __shfl_xor(sum, 8, 64);
      lrow[r] = lrow[r] * alpha + sum;
#pragma unroll
      for (int jn = 0; jn < 4; ++jn) o[jn][r] *= alpha;
    }

    // P: C layout -> A layout via wave-private LDS (same-wave DS order: no barrier)
#pragma unroll
    for (int r = 0; r < 4; ++r)
#pragma unroll
      for (int jn = 0; jn < 4; ++jn)
        psw[(l4 * 4 + r) * 72 + jn * 16 + l15] = (short)f2bf(sc[jn][r]);

    short8 pf0 = *(const short8*)(psw + l15 * 72 + l4 * 8);
    short8 pf1 = *(const short8*)(psw + l15 * 72 + 32 + l4 * 8);

#pragma unroll
    for (int jn = 0; jn < 4; ++jn) {
      const short* pvt = Vt + (jn * 16 + l15) * 72 + l4 * 8;
      short8 v0 = *(const short8*)pvt;
      short8 v1 = *(const short8*)(pvt + 32);
      o[jn] = __builtin_amdgcn_mfma_f32_16x16x32_bf16(pf0, v0, o[jn], 0, 0, 0);
      o[jn] = __builtin_amdgcn_mfma_f32_16x16x32_bf16(pf1, v1, o[jn], 0, 0, 0);
    }
  }

  unsigned short* so = (unsigned short*)sa + (size_t)(bh * 128 + qt * 4 + wave) * 1024;
#pragma unroll
  for (int r = 0; r < 4; ++r) {
    const float inv = 1.0f / lrow[r];
    const int qloc = l4 * 4 + r;
#pragma unroll
    for (int jn = 0; jn < 4; ++jn)
      so[qloc * 64 + jn * 16 + l15] = f2bf(o[jn][r] * inv);
  }
}

extern "C" void kernel_launch(void* const* d_in, const int* in_sizes, int n_in,
                              void* d_out, int out_size, void* d_ws, size_t ws_size,
                              hipStream_t stream)
{
  const void* x_raw    = d_in[0];  // [4,2048,1024]
  const void* Wqkv_raw = d_in[1];  // [1024,3072]
  const void* bqkv_raw = d_in[2];  // [3072]
  const void* Wout_raw = d_in[3];  // [1024,1024]
  const void* bout_raw = d_in[4];  // [1024]

  char* ws = (char*)d_ws;
  int*  flag   = (int*)ws;                                  //   256 B
  bf16* xb     = (bf16*)(ws + 256);                         //  16 MiB (8192*1024)
  bf16* wqkvT  = xb + (size_t)8192 * 1024;                  //   6 MiB (3072*1024, [N][K])
  bf16* bqkvb  = wqkvT + (size_t)3072 * 1024;               //   6 KiB
  bf16* woutT  = bqkvb + 4096;                              //   2 MiB (1024*1024, [N][K])
  bf16* boutb  = woutT + (size_t)1024 * 1024;               //   2 KiB
  bf16* qkv    = boutb + 4096;                              //  48 MiB (8192*3072)
  bf16* sa     = qkv + (size_t)8192 * 3072;                 //  16 MiB (8192*1024)

  detect_kernel<<<1, 64, 0, stream>>>((const unsigned int*)x_raw, flag);

  auto conv = [&](const void* src, bf16* dst, int n) {
    int n8 = n / 8;
    convert_kernel<<<(n8 + 255) / 256, 256, 0, stream>>>(src, dst, n8, flag);
  };
  conv(x_raw, xb, 8192 * 1024);
  conv(bqkv_raw, bqkvb, 3072);
  conv(bout_raw, boutb, 1024);
  transpose_bf16<<<dim3(3072 / 32, 1024 / 32), 256, 0, stream>>>(Wqkv_raw, wqkvT, 1024, 3072, flag);
  transpose_bf16<<<dim3(1024 / 32, 1024 / 32), 256, 0, stream>>>(Wout_raw, woutT, 1024, 1024, flag);

  // 1) qkv = x @ W_qkv + b_qkv   (M=8192, N=3072, K=1024)
  gemm_mfma<<<dim3(3072 / 128, 8192 / 128), 256, 0, stream>>>(
      xb, wqkvT, bqkvb, qkv, 8192, 3072, 1024, 0, flag);
  // 2) MFMA flash attention (LPT grid: x=bh, y=qt-reversed)
  attn_mfma<<<dim3(64, 32), 256, 0, stream>>>(qkv, sa);
  // 3) out = sa @ W_out + b_out  (M=8192, N=1024, K=1024)
  gemm_mfma<<<dim3(1024 / 128, 8192 / 128), 256, 0, stream>>>(
      sa, woutT, boutb, d_out, 8192, 1024, 1024, 1, flag);
}